// Round 6
// baseline (76.598 us; speedup 1.0000x reference)
//
#include <hip/hip_runtime.h>

typedef __attribute__((ext_vector_type(8))) short bf16x8;
typedef __attribute__((ext_vector_type(4))) float f32x4;

constexpr int N       = 50000;
constexpr int NE      = 800000;
constexpr int AD      = 128;   // ATOM_DIM
constexpr int BD      = 16;    // BOND_DIM
constexpr int BD2     = 256;   // BD*BD
constexpr int HIDDEN  = 128;
constexpr int NB      = 64;    // nodes per block
constexpr int SSTR    = 20;    // S tile stride (floats) - bank-friendly
constexpr int OSTR    = 132;   // out repack stride (floats) - 2-way-free

// f32 -> bf16 round-to-nearest-even
__device__ inline short f2bf(float f) {
    union U { float f; unsigned u; } v; v.f = f;
    unsigned r = v.u + 0x7fffu + ((v.u >> 16) & 1u);
    return (short)(r >> 16);
}

// ---------------------------------------------------------------------------
// Kernel 0: build bf16 fragment-linear operand tables (kmat, Wn|Wi padded).
// ---------------------------------------------------------------------------
__global__ __launch_bounds__(256) void prep_frags(
    const float* __restrict__ kmat,
    const float* __restrict__ Wn,
    const float* __restrict__ Wi,
    short* __restrict__ kbf,
    short* __restrict__ wbf)
{
    int t = blockIdx.x * 256 + threadIdx.x;
    if (t < 4096) {
        int u = t >> 6, l = t & 63;
        int nf = u >> 2, kk = u & 3;
        int col = nf * 16 + (l & 15);
        int k0  = kk * 32 + (l >> 4) * 8;
        bf16x8 o;
#pragma unroll
        for (int j = 0; j < 8; ++j) o[j] = f2bf(kmat[(size_t)(k0 + j) * BD2 + col]);
        *(bf16x8*)(kbf + (size_t)t * 8) = o;
    } else if (t < 4096 + 1024) {
        int t2 = t - 4096;
        int u = t2 >> 6, l = t2 & 63;
        int m = u >> 3, nf2 = u & 7;
        const float* W = m ? Wi : Wn;
        int col = nf2 * 16 + (l & 15);
        int k0  = (l >> 4) * 8;
        bf16x8 o;
#pragma unroll
        for (int j = 0; j < 8; ++j) {
            int k = k0 + j;
            o[j] = (k < 16) ? f2bf(W[(size_t)k * HIDDEN + col]) : (short)0;
        }
        *(bf16x8*)(wbf + (size_t)t2 * 8) = o;
    }
}

// ---------------------------------------------------------------------------
// Kernel 1: everything fused. One block = 64 nodes.
//  phase A: windowed binary search for this block's edge range (src-sorted)
//  phase B: segment-sum bonds[nbr] into LDS S tile (16 groups, LDS atomics)
//  phase C: MFMA GEMM (swapped operands) + lane-local S contraction
//  phase D: epilogue MFMAs -> LDS repack -> coalesced nontemporal float4
//           stores of all 4 output copies
// ---------------------------------------------------------------------------
__global__ __launch_bounds__(256, 4) void fused_all(
    const float* __restrict__ atoms,
    const float* __restrict__ bonds,
    const int*  __restrict__ pairs,   // 2*NE ints, sorted by src
    const short* __restrict__ kbf,    // 64KB fragment-linear kmat
    const short* __restrict__ wbf,    // 16KB fragment-linear Wn|Wi
    const float* __restrict__ bias,   // 256
    float* __restrict__ out)          // 4 x N x 128
{
    __shared__ float lds[NB * OSTR];  // 33.8KB; phase B/C: S tile at stride SSTR

    const int tid = threadIdx.x;
    const int w   = tid >> 6;
    const int l   = tid & 63;
    const int lq  = l >> 4;
    const int lj  = l & 15;
    const int nb  = blockIdx.x * NB;
    const int wrow = nb + w * 16;

    // ---- issue atoms loads early (independent of everything) --------------
    int arow = wrow + lj; if (arow >= N) arow = N - 1;
    const float* ap = atoms + (size_t)arow * AD + lq * 8;
    float4 a0[4], a1[4];
#pragma unroll
    for (int kk = 0; kk < 4; ++kk) {
        a0[kk] = *(const float4*)(ap + kk * 32);
        a1[kk] = *(const float4*)(ap + kk * 32 + 4);
    }

    // ---- phase A: edge range via validated windowed binary search ---------
    int wlo = nb * 16 - 4096; if (wlo < 0) wlo = 0;
    int whi = (nb + NB) * 16 + 4096; if (whi > NE) whi = NE;
    if (wlo > 0  && pairs[2 * wlo] >= nb)      wlo = 0;   // window too high
    if (whi < NE && pairs[2 * whi] <  nb + NB) whi = NE;  // window too low
    int eLo;
    {
        int s = wlo, e = whi;
        while (s < e) { int m = (s + e) >> 1; if (pairs[2 * m] < nb) s = m + 1; else e = m; }
        eLo = s;
    }
    int eHi;
    {
        int s = eLo, e = whi;
        while (s < e) { int m = (s + e) >> 1; if (pairs[2 * m] < nb + NB) s = m + 1; else e = m; }
        eHi = s;
    }

    // ---- phase B: zero S tile, segment-sum into it ------------------------
    for (int i = tid; i < NB * SSTR; i += 256) lds[i] = 0.f;
    __syncthreads();

    {
        const int g = tid >> 4;      // 16 groups
        const int c = tid & 15;      // component
        const int nE = eHi - eLo;
        const int cg = (nE + 15) >> 4;
        int gs = eLo + g * cg;
        int ge = gs + cg; if (ge > eHi) ge = eHi;
        int cur = -1; float acc = 0.f;
        int e = gs;
        for (; e + 4 <= ge; e += 4) {
            int2 pb[4]; float vb[4];
#pragma unroll
            for (int i = 0; i < 4; ++i) pb[i] = *(const int2*)(pairs + 2 * (e + i));
#pragma unroll
            for (int i = 0; i < 4; ++i) vb[i] = bonds[(size_t)pb[i].y * BD + c];
#pragma unroll
            for (int i = 0; i < 4; ++i) {
                if (pb[i].x != cur) {
                    if (cur >= 0) atomicAdd(&lds[(cur - nb) * SSTR + c], acc);
                    acc = 0.f; cur = pb[i].x;
                }
                acc += vb[i];
            }
        }
        for (; e < ge; ++e) {
            int2 p = *(const int2*)(pairs + 2 * e);
            float v = bonds[(size_t)p.y * BD + c];
            if (p.x != cur) {
                if (cur >= 0) atomicAdd(&lds[(cur - nb) * SSTR + c], acc);
                acc = 0.f; cur = p.x;
            }
            acc += v;
        }
        if (cur >= 0) atomicAdd(&lds[(cur - nb) * SSTR + c], acc);
    }
    __syncthreads();

    // ---- read S for this lane's node, then free the LDS tile --------------
    float4 sv = *(const float4*)(&lds[(w * 16 + lj) * SSTR + lq * 4]);
    __syncthreads();   // all S reads done before repack overwrites

    // ---- phase C: bf16 A-fragments + main GEMM (swapped operands) ---------
    bf16x8 afrag[4];
#pragma unroll
    for (int kk = 0; kk < 4; ++kk) {
        bf16x8 af;
        af[0] = f2bf(a0[kk].x); af[1] = f2bf(a0[kk].y);
        af[2] = f2bf(a0[kk].z); af[3] = f2bf(a0[kk].w);
        af[4] = f2bf(a1[kk].x); af[5] = f2bf(a1[kk].y);
        af[6] = f2bf(a1[kk].z); af[7] = f2bf(a1[kk].w);
        afrag[kk] = af;
    }

    f32x4 acc[16];
#pragma unroll
    for (int nf = 0; nf < 16; ++nf) acc[nf] = (f32x4){0.f, 0.f, 0.f, 0.f};

    const bf16x8* kb = (const bf16x8*)kbf;
#pragma unroll 1
    for (int kk = 0; kk < 4; ++kk) {
#pragma unroll
        for (int nf = 0; nf < 16; ++nf) {
            bf16x8 b = kb[(size_t)(nf * 4 + kk) * 64 + l];
            acc[nf] = __builtin_amdgcn_mfma_f32_16x16x32_bf16(b, afrag[kk], acc[nf], 0, 0, 0);
        }
    }

    // ---- contraction with S: every lane ends with agg[lj][0..15] ----------
    float aggf[16];
#pragma unroll
    for (int nf = 0; nf < 16; ++nf) {
        float4 bv = *(const float4*)(bias + nf * 16 + lq * 4);
        float q = (acc[nf][0] + bv.x) * sv.x
                + (acc[nf][1] + bv.y) * sv.y
                + (acc[nf][2] + bv.z) * sv.z
                + (acc[nf][3] + bv.w) * sv.w;
        q += __shfl_xor(q, 16);
        q += __shfl_xor(q, 32);
        aggf[nf] = q;
    }

    // ---- phase D: epilogue fragments (K=16 zero-padded to 32) -------------
    bf16x8 agg_a  = (bf16x8){0,0,0,0,0,0,0,0};
    bf16x8 bond_a = (bf16x8){0,0,0,0,0,0,0,0};
    if (lq < 2) {
#pragma unroll
        for (int j = 0; j < 8; ++j) agg_a[j] = f2bf(aggf[lq * 8 + j]);
        int brow = wrow + lj; if (brow >= N) brow = N - 1;
        float4 b0 = *(const float4*)(bonds + (size_t)brow * BD + lq * 8);
        float4 b1 = *(const float4*)(bonds + (size_t)brow * BD + lq * 8 + 4);
        bond_a[0] = f2bf(b0.x); bond_a[1] = f2bf(b0.y);
        bond_a[2] = f2bf(b0.z); bond_a[3] = f2bf(b0.w);
        bond_a[4] = f2bf(b1.x); bond_a[5] = f2bf(b1.y);
        bond_a[6] = f2bf(b1.z); bond_a[7] = f2bf(b1.w);
    }

    // epilogue MFMAs; results into LDS repack tile (stride OSTR)
    const bf16x8* wb = (const bf16x8*)wbf;
#pragma unroll
    for (int nf2 = 0; nf2 < 8; ++nf2) {
        bf16x8 wn_f = wb[(size_t)nf2 * 64 + l];
        bf16x8 wi_f = wb[(size_t)(8 + nf2) * 64 + l];
        f32x4 e = __builtin_amdgcn_mfma_f32_16x16x32_bf16(
            bond_a, wi_f, (f32x4){0.f, 0.f, 0.f, 0.f}, 0, 0, 0);
        e[0] = fmaxf(e[0], 0.f); e[1] = fmaxf(e[1], 0.f);
        e[2] = fmaxf(e[2], 0.f); e[3] = fmaxf(e[3], 0.f);
        f32x4 o = __builtin_amdgcn_mfma_f32_16x16x32_bf16(agg_a, wn_f, e, 0, 0, 0);
#pragma unroll
        for (int r = 0; r < 4; ++r) {
            int nl = w * 16 + 4 * lq + r;          // node within block
            lds[nl * OSTR + nf2 * 16 + lj] = fmaxf(o[r], 0.f);
        }
    }
    __syncthreads();

    // ---- coalesced nontemporal f32x4 stores, 4 copies ---------------------
#pragma unroll
    for (int p = 0; p < 8; ++p) {
        int idx  = tid + 256 * p;
        int nl   = idx >> 5;           // node within block
        int h4   = (idx & 31) * 4;     // hidden offset
        int node = nb + nl;
        if (node < N) {
            f32x4 v = *(const f32x4*)(&lds[nl * OSTR + h4]);
            float* dst = out + (size_t)node * HIDDEN + h4;
#pragma unroll
            for (int s = 0; s < 4; ++s) {
                __builtin_nontemporal_store(v, (f32x4*)(dst + (size_t)s * N * HIDDEN));
            }
        }
    }
}

// ---------------------------------------------------------------------------
extern "C" void kernel_launch(void* const* d_in, const int* in_sizes, int n_in,
                              void* d_out, int out_size, void* d_ws, size_t ws_size,
                              hipStream_t stream)
{
    const float* atoms = (const float*)d_in[0];
    const float* bonds = (const float*)d_in[1];
    const int*   pairs = (const int*)d_in[2];
    const float* kmat  = (const float*)d_in[3];
    const float* bias  = (const float*)d_in[4];
    const float* Wn    = (const float*)d_in[5];
    const float* Wi    = (const float*)d_in[6];
    float* out = (float*)d_out;

    short* kbf = (short*)d_ws;          // 64KB
    short* wbf = kbf + 4096 * 8;        // 16KB

    prep_frags<<<20, 256, 0, stream>>>(kmat, Wn, Wi, kbf, wbf);

    fused_all<<<(N + NB - 1) / NB, 256, 0, stream>>>(
        atoms, bonds, pairs, kbf, wbf, bias, out);
}